// Round 5
// baseline (83.530 us; speedup 1.0000x reference)
//
#include <hip/hip_runtime.h>

#define HH 128
#define WW 256
#define CV_C 32
#define DISP 200

typedef __attribute__((ext_vector_type(4))) float f32x4;
typedef __attribute__((ext_vector_type(8))) short bf16x8;

__device__ inline unsigned short f2bf(float f) {
  unsigned int u = __float_as_uint(f);
  u = (u + 0x7FFFu + ((u >> 16) & 1u)) >> 16;  // RNE
  return (unsigned short)u;
}

__device__ inline float bf2f(short s) {
  return __uint_as_float(((unsigned int)(unsigned short)s) << 16);
}

// ---------------------------------------------------------------------------
// K1: weight packs (blocks 0..593) || cost-volume MFMA band-matmul (594..1105)
// CV: cost[d,y,x] = sum_c L[c,y,x]*R[c,y,x+d-200] -> cost_t bf16 [128][256][224]
// ---------------------------------------------------------------------------
__global__ __launch_bounds__(256) void k1_pack_cv(
    const float* __restrict__ left, const float* __restrict__ right,
    const float* __restrict__ w1, const float* __restrict__ w2,
    const float* __restrict__ w3, unsigned short* __restrict__ pw1,
    unsigned short* __restrict__ pb2, unsigned short* __restrict__ pb3,
    unsigned short* __restrict__ cost_t) {
  __shared__ unsigned short r_sh[272][40];  // 21760 B
  __shared__ unsigned short l_hi[64][40];   // 5120 B
  __shared__ unsigned short l_lo[64][40];   // 5120 B
  __shared__ unsigned short c_sh[64][224];  // 28672 B
  const int bx = blockIdx.x;
  const int tid = threadIdx.x;

  if (bx < 594) {  // ---- weight packing ----
    if (bx < 504) {  // pw1[chunk 7][pos 9][kg 4][n 64][j 8]
      const int idx = bx * 256 + tid;
      const int j = idx & 7;
      const int n = (idx >> 3) & 63;
      const int kg = (idx >> 9) & 3;
      const int cp = idx >> 11;
      const int pos = cp % 9;
      const int chunk = cp / 9;
      const int ci = chunk * 32 + kg * 8 + j;
      float v = 0.f;
      if (ci < 200) v = w1[(n * 200 + ci) * 9 + pos];
      pw1[idx] = f2bf(v);
    } else if (bx < 576) {  // pb2[pos 9][kc 2][kg 4][n 32][j 8]
      const int idx = (bx - 504) * 256 + tid;
      const int j = idx & 7;
      const int n = (idx >> 3) & 31;
      const int kg = (idx >> 8) & 3;
      const int kc = (idx >> 10) & 1;
      const int pos = idx >> 11;
      const int ci = kc * 32 + kg * 8 + j;
      pb2[idx] = f2bf(w2[(n * 64 + ci) * 9 + pos]);
    } else {  // pb3[pos 9][kg 4][n 16(8 real)][j 8]
      const int idx = (bx - 576) * 256 + tid;
      const int j = idx & 7;
      const int n = (idx >> 3) & 15;
      const int kg = (idx >> 7) & 3;
      const int pos = idx >> 9;
      const int ci = kg * 8 + j;
      float v = 0.f;
      if (n < 8) v = w3[(n * 32 + ci) * 9 + pos];
      pb3[idx] = f2bf(v);
    }
    return;
  }

  // ---- cost volume (round-4 proven body) ----
  const int idx = bx - 594;
  const int y = idx & 127;
  const int x0 = (idx >> 7) * 64;
  const int lane = tid & 63;
  const int w = tid >> 6;
  const int col = lane & 15;
  const int kg = lane >> 4;

  for (int c = w; c < CV_C; c += 4) {
    const float v = left[(c * HH + y) * WW + x0 + lane];
    const unsigned short h = f2bf(v);
    l_hi[lane][c] = h;
    l_lo[lane][c] = f2bf(v - bf2f(h));
  }
  for (int c = w; c < CV_C; c += 4) {
    for (int pb = 0; pb < 320; pb += 64) {
      const int p = pb + lane;
      if (p < 272) {
        const int xp = x0 - 208 + p;
        float v = (xp >= 0) ? right[(c * HH + y) * WW + xp] : 0.f;
        r_sh[p][c] = f2bf(v);
      }
    }
  }
  {
    bf16x8 z = {0, 0, 0, 0, 0, 0, 0, 0};
    bf16x8* cz = (bf16x8*)c_sh;
#pragma unroll
    for (int k = 0; k < 7; ++k) cz[k * 256 + tid] = z;
  }
  __syncthreads();

  const bf16x8 b_hi = *(const bf16x8*)&l_hi[16 * w + col][kg * 8];
  const bf16x8 b_lo = *(const bf16x8*)&l_lo[16 * w + col][kg * 8];

  for (int t = 0; t < 14; ++t) {
    const int pb = 16 * (w - t) + 208;
    const bf16x8 a_r = *(const bf16x8*)&r_sh[pb + col][kg * 8];
    f32x4 acc = {0.f, 0.f, 0.f, 0.f};
    acc = __builtin_amdgcn_mfma_f32_16x16x32_bf16(a_r, b_hi, acc, 0, 0, 0);
    acc = __builtin_amdgcn_mfma_f32_16x16x32_bf16(a_r, b_lo, acc, 0, 0, 0);
#pragma unroll
    for (int r = 0; r < 4; ++r) {
      const int d = 200 - 16 * t + kg * 4 + r - col;
      if (d >= 0 && d < DISP) c_sh[16 * w + col][d] = f2bf(acc[r]);
    }
  }
  __syncthreads();

#pragma unroll
  for (int k = 0; k < 7; ++k) {
    const int s = k * 256 + tid;
    const int x = s / 28;
    const int dv = s - x * 28;
    *reinterpret_cast<bf16x8*>(&cost_t[(y * WW + x0 + x) * 224 + dv * 8]) =
        *reinterpret_cast<const bf16x8*>(&c_sh[x][dv * 8]);
  }
}

// ---------------------------------------------------------------------------
// K2: conv1 implicit GEMM bf16 MFMA. 2 output rows/block, grid (4,64).
// Waves: w -> row r = w>>1, m-half mh = (w&1)*32. Each wave: 2M x 4N tiles.
// A staged rows y0-1..y0+2 (4) x 66 cols per 32-ci chunk, double-buffered.
// ---------------------------------------------------------------------------
__global__ __launch_bounds__(256) void conv1_mfma_kernel(
    const unsigned short* __restrict__ cost_t,  // [128][256][224]
    const unsigned short* __restrict__ pw,      // [7][9][4][64][8]
    const float* __restrict__ bias, const float* __restrict__ gam,
    const float* __restrict__ bet, const float* __restrict__ mean,
    const float* __restrict__ var, unsigned short* __restrict__ out_t) {
  __shared__ unsigned short a_sh[2][4 * 66 * 40];  // 42240 B
  const int tid = threadIdx.x;
  const int lane = tid & 63;
  const int w = tid >> 6;
  const int y0 = blockIdx.y * 2;
  const int x0 = blockIdx.x * 64;
  const int r = w >> 1;
  const int mh = (w & 1) * 32;
  const int col = lane & 15;
  const int kg = lane >> 4;

  // per-thread staging slots (chunk-independent): 1056 = 4*66*4 vec8 slots
  long goff[5];
  int laddr[5];
  bool gvalid[5], lvalid[5];
#pragma unroll
  for (int it = 0; it < 5; ++it) {
    const int i = tid + it * 256;
    lvalid[it] = i < 1056;
    const int row = i / 264;
    const int rem = i % 264;
    const int xx = rem >> 2;
    const int q = rem & 3;
    const int gy = y0 + row - 1;
    const int gx = x0 - 1 + xx;
    gvalid[it] = lvalid[it] && gy >= 0 && gy < HH && gx >= 0 && gx < WW;
    goff[it] = gvalid[it] ? (long)(gy * WW + gx) * 224 + q * 8 : 0;
    laddr[it] = (row * 66 + xx) * 40 + q * 8;
  }

  f32x4 acc[2][4];
#pragma unroll
  for (int i = 0; i < 2; ++i)
#pragma unroll
    for (int jj = 0; jj < 4; ++jj) acc[i][jj] = 0.f;

  const bf16x8* pwv = (const bf16x8*)pw;
  const bf16x8 zero = {0, 0, 0, 0, 0, 0, 0, 0};
  bf16x8 stg[5];

  // prologue: stage chunk 0
#pragma unroll
  for (int it = 0; it < 5; ++it)
    stg[it] = gvalid[it] ? *reinterpret_cast<const bf16x8*>(&cost_t[goff[it]])
                         : zero;
#pragma unroll
  for (int it = 0; it < 5; ++it)
    if (lvalid[it]) *reinterpret_cast<bf16x8*>(&a_sh[0][laddr[it]]) = stg[it];
  __syncthreads();

  for (int chunk = 0; chunk < 7; ++chunk) {
    const int buf = chunk & 1;
    if (chunk < 6) {
#pragma unroll
      for (int it = 0; it < 5; ++it)
        stg[it] = gvalid[it] ? *reinterpret_cast<const bf16x8*>(
                                   &cost_t[goff[it] + (chunk + 1) * 32])
                             : zero;
    }
    const bf16x8* av = (const bf16x8*)a_sh[buf];
#pragma unroll
    for (int pos = 0; pos < 9; ++pos) {
      const int ky = pos / 3;
      const int kx = pos % 3;
      const int bbase = ((chunk * 9 + pos) * 4 + kg) * 64;
      bf16x8 bv[4];
#pragma unroll
      for (int nt = 0; nt < 4; ++nt) bv[nt] = pwv[bbase + nt * 16 + col];
      const bf16x8 a0v = av[((r + ky) * 66 + mh + col + kx) * 5 + kg];
      const bf16x8 a1v = av[((r + ky) * 66 + mh + 16 + col + kx) * 5 + kg];
#pragma unroll
      for (int nt = 0; nt < 4; ++nt) {
        acc[0][nt] =
            __builtin_amdgcn_mfma_f32_16x16x32_bf16(a0v, bv[nt], acc[0][nt], 0, 0, 0);
        acc[1][nt] =
            __builtin_amdgcn_mfma_f32_16x16x32_bf16(a1v, bv[nt], acc[1][nt], 0, 0, 0);
      }
    }
    if (chunk < 6) {
#pragma unroll
      for (int it = 0; it < 5; ++it)
        if (lvalid[it])
          *reinterpret_cast<bf16x8*>(&a_sh[buf ^ 1][laddr[it]]) = stg[it];
      __syncthreads();
    }
  }

  // epilogue: bias + BN + ReLU -> o1_t NHWC bf16 [128][256][64]
  const int y = y0 + r;
#pragma unroll
  for (int nt = 0; nt < 4; ++nt) {
    const int c = nt * 16 + col;
    const float inv = rsqrtf(var[c] + 1e-5f);
    const float sc = gam[c] * inv;
    const float sh = bet[c] - mean[c] * sc;
    const float bb = bias[c];
#pragma unroll
    for (int mf = 0; mf < 2; ++mf) {
#pragma unroll
      for (int rr = 0; rr < 4; ++rr) {
        const int m = mh + mf * 16 + kg * 4 + rr;
        float vv = (acc[mf][nt][rr] + bb) * sc + sh;
        vv = fmaxf(vv, 0.f);
        out_t[((y * WW + x0 + m) << 6) + c] = f2bf(vv);
      }
    }
  }
}

// ---------------------------------------------------------------------------
// K3: fused conv2+conv3+conv4. Block: 2 final rows x 64 px, grid (4,64).
// o1 tile (8 rows x 82 cols x 64ch, swizzled) -> conv2 -> o2 tile (6x84x40pad)
// -> conv3 -> o3 tile (4x66x24pad) -> conv4 -> out f32.
// SAME padding realized by zeroing out-of-image scatter slots.
// ---------------------------------------------------------------------------
__global__ __launch_bounds__(256) void k3_fused(
    const unsigned short* __restrict__ o1t,  // [128][256][64]
    const unsigned short* __restrict__ pb2,  // [9][2][4][32][8]
    const unsigned short* __restrict__ pb3,  // [9][4][16][8]
    const float* __restrict__ b2, const float* __restrict__ g2,
    const float* __restrict__ be2, const float* __restrict__ m2,
    const float* __restrict__ v2, const float* __restrict__ b3,
    const float* __restrict__ g3, const float* __restrict__ be3,
    const float* __restrict__ m3, const float* __restrict__ v3,
    const float* __restrict__ w4, const float* __restrict__ b4,
    float* __restrict__ out) {
  __shared__ unsigned short o1s[656 * 64];  // 8 rows x 82 cols, 83968 B
  __shared__ unsigned short o2s[504 * 40];  // 6 rows x 84 cols, 40320 B
  __shared__ unsigned short o3s[264 * 24];  // 4 rows x 66 cols, 12672 B
  char* const o1b = (char*)o1s;
  const int tid = threadIdx.x;
  const int lane = tid & 63;
  const int w = tid >> 6;
  const int y0 = blockIdx.y * 2;
  const int x0 = blockIdx.x * 64;
  const int col = lane & 15;
  const int kg = lane >> 4;

  // per-lane BN constants (fixed c per lane across all jobs)
  float sc2[2], sh2[2], bb2[2];
#pragma unroll
  for (int nh = 0; nh < 2; ++nh) {
    const int c = nh * 16 + col;
    const float inv = rsqrtf(v2[c] + 1e-5f);
    sc2[nh] = g2[c] * inv;
    sh2[nh] = be2[c] - m2[c] * sc2[nh];
    bb2[nh] = b2[c];
  }
  const int c3 = col < 8 ? col : 7;
  const float inv3 = rsqrtf(v3[c3] + 1e-5f);
  const float sc3 = g3[c3] * inv3;
  const float sh3 = be3[c3] - m3[c3] * sc3;
  const float bb3 = b3[c3];

  // ---- stage o1 tile: rows y0-3..y0+4, cols x0-3..x0+78, swizzled ----
  for (int i = tid; i < 5248; i += 256) {  // 656 slots x 8 q
    const int r2 = i >> 3;
    const int q = i & 7;
    const int row = r2 / 82;
    const int xx = r2 % 82;
    const int gy = y0 - 3 + row;
    const int gx = x0 - 3 + xx;
    bf16x8 v = {0, 0, 0, 0, 0, 0, 0, 0};
    if (gy >= 0 && gy < HH && gx >= 0 && gx < WW)
      v = *reinterpret_cast<const bf16x8*>(&o1t[((gy * WW + gx) << 6) + q * 8]);
    const int byte = (r2 * 128 + q * 16) ^ ((r2 & 7) << 4);
    *reinterpret_cast<bf16x8*>(o1b + byte) = v;
  }
  __syncthreads();

  // ---- conv2: 30 jobs (6 rows x 5 x-tiles), paired for MFMA ILP ----
  const bf16x8* pbv2 = (const bf16x8*)pb2;
  for (int base = w; base < 30; base += 8) {
    const int j0 = base, j1 = base + 4;
    const bool has1 = j1 < 30;
    const int ro0 = j0 / 5, t0 = j0 % 5;
    const int ro1 = has1 ? j1 / 5 : 0, t1 = has1 ? j1 % 5 : 0;
    f32x4 acA[2] = {{0.f, 0.f, 0.f, 0.f}, {0.f, 0.f, 0.f, 0.f}};
    f32x4 acB[2] = {{0.f, 0.f, 0.f, 0.f}, {0.f, 0.f, 0.f, 0.f}};
#pragma unroll
    for (int pos = 0; pos < 9; ++pos) {
      const int ky = pos / 3;
      const int kx = pos % 3;
#pragma unroll
      for (int kc = 0; kc < 2; ++kc) {
        const bf16x8 bv0 = pbv2[((pos * 2 + kc) * 4 + kg) * 32 + col];
        const bf16x8 bv1 = pbv2[((pos * 2 + kc) * 4 + kg) * 32 + 16 + col];
        const int ra = (ro0 + ky) * 82 + 16 * t0 + col + kx;
        const bf16x8 a0 = *reinterpret_cast<const bf16x8*>(
            o1b + ((ra * 128 + (kc * 4 + kg) * 16) ^ ((ra & 7) << 4)));
        acA[0] = __builtin_amdgcn_mfma_f32_16x16x32_bf16(a0, bv0, acA[0], 0, 0, 0);
        acA[1] = __builtin_amdgcn_mfma_f32_16x16x32_bf16(a0, bv1, acA[1], 0, 0, 0);
        if (has1) {
          const int rb = (ro1 + ky) * 82 + 16 * t1 + col + kx;
          const bf16x8 a1 = *reinterpret_cast<const bf16x8*>(
              o1b + ((rb * 128 + (kc * 4 + kg) * 16) ^ ((rb & 7) << 4)));
          acB[0] = __builtin_amdgcn_mfma_f32_16x16x32_bf16(a1, bv0, acB[0], 0, 0, 0);
          acB[1] = __builtin_amdgcn_mfma_f32_16x16x32_bf16(a1, bv1, acB[1], 0, 0, 0);
        }
      }
    }
    // scatter j0 (and j1): px2 local col in o2 tile, zero outside image
#pragma unroll
    for (int nh = 0; nh < 2; ++nh) {
      const int c = nh * 16 + col;
#pragma unroll
      for (int rr = 0; rr < 4; ++rr) {
        const int px2 = 16 * t0 + kg * 4 + rr;
        if (px2 < 68) {
          const int gy2 = y0 - 2 + ro0;
          const int gx2 = x0 - 2 + px2;
          float vv = 0.f;
          if (gy2 >= 0 && gy2 < HH && gx2 >= 0 && gx2 < WW)
            vv = fmaxf((acA[nh][rr] + bb2[nh]) * sc2[nh] + sh2[nh], 0.f);
          o2s[(ro0 * 84 + px2) * 40 + c] = f2bf(vv);
        }
        if (has1) {
          const int px2b = 16 * t1 + kg * 4 + rr;
          if (px2b < 68) {
            const int gy2 = y0 - 2 + ro1;
            const int gx2 = x0 - 2 + px2b;
            float vv = 0.f;
            if (gy2 >= 0 && gy2 < HH && gx2 >= 0 && gx2 < WW)
              vv = fmaxf((acB[nh][rr] + bb2[nh]) * sc2[nh] + sh2[nh], 0.f);
            o2s[(ro1 * 84 + px2b) * 40 + c] = f2bf(vv);
          }
        }
      }
    }
  }
  __syncthreads();

  // ---- conv3: 20 jobs (4 rows x 5 x-tiles), paired ----
  const bf16x8* pbv3 = (const bf16x8*)pb3;
  const bf16x8* o2v = (const bf16x8*)o2s;
  for (int base = w; base < 20; base += 8) {
    const int j0 = base, j1 = base + 4;
    const bool has1 = j1 < 20;
    const int ro0 = j0 / 5, t0 = j0 % 5;
    const int ro1 = has1 ? j1 / 5 : 0, t1 = has1 ? j1 % 5 : 0;
    f32x4 acA = {0.f, 0.f, 0.f, 0.f};
    f32x4 acB = {0.f, 0.f, 0.f, 0.f};
#pragma unroll
    for (int pos = 0; pos < 9; ++pos) {
      const int ky = pos / 3;
      const int kx = pos % 3;
      const bf16x8 bv = pbv3[(pos * 4 + kg) * 16 + col];
      const bf16x8 a0 = o2v[((ro0 + ky) * 84 + 16 * t0 + col + kx) * 5 + kg];
      acA = __builtin_amdgcn_mfma_f32_16x16x32_bf16(a0, bv, acA, 0, 0, 0);
      if (has1) {
        const bf16x8 a1 = o2v[((ro1 + ky) * 84 + 16 * t1 + col + kx) * 5 + kg];
        acB = __builtin_amdgcn_mfma_f32_16x16x32_bf16(a1, bv, acB, 0, 0, 0);
      }
    }
    if (col < 8) {
#pragma unroll
      for (int rr = 0; rr < 4; ++rr) {
        const int px3 = 16 * t0 + kg * 4 + rr;
        if (px3 < 66) {
          const int gy3 = y0 - 1 + ro0;
          const int gx3 = x0 - 1 + px3;
          float vv = 0.f;
          if (gy3 >= 0 && gy3 < HH && gx3 >= 0 && gx3 < WW)
            vv = fmaxf((acA[rr] + bb3) * sc3 + sh3, 0.f);
          o3s[(ro0 * 66 + px3) * 24 + col] = f2bf(vv);
        }
        if (has1) {
          const int px3b = 16 * t1 + kg * 4 + rr;
          if (px3b < 66) {
            const int gy3 = y0 - 1 + ro1;
            const int gx3 = x0 - 1 + px3b;
            float vv = 0.f;
            if (gy3 >= 0 && gy3 < HH && gx3 >= 0 && gx3 < WW)
              vv = fmaxf((acB[rr] + bb3) * sc3 + sh3, 0.f);
            o3s[(ro1 * 66 + px3b) * 24 + col] = f2bf(vv);
          }
        }
      }
    }
  }
  __syncthreads();

  // ---- conv4: 8->1, threads 0..127 each produce one output pixel ----
  if (tid < 128) {
    const int ry = tid >> 6;
    const int x = tid & 63;
    float wr[3][3][8];
#pragma unroll
    for (int ci = 0; ci < 8; ++ci)
#pragma unroll
      for (int ky = 0; ky < 3; ++ky)
#pragma unroll
        for (int kx = 0; kx < 3; ++kx)
          wr[ky][kx][ci] = w4[(ci * 3 + ky) * 3 + kx];
    float acc = b4[0];
    const bf16x8* o3v = (const bf16x8*)o3s;
#pragma unroll
    for (int ky = 0; ky < 3; ++ky) {
#pragma unroll
      for (int kx = 0; kx < 3; ++kx) {
        const bf16x8 v = o3v[((ry + ky) * 66 + x + kx) * 3];
#pragma unroll
        for (int ci = 0; ci < 8; ++ci) acc += bf2f(v[ci]) * wr[ky][kx][ci];
      }
    }
    out[(y0 + ry) * WW + x0 + x] = acc;
  }
}

// ---------------------------------------------------------------------------
extern "C" void kernel_launch(void* const* d_in, const int* in_sizes, int n_in,
                              void* d_out, int out_size, void* d_ws,
                              size_t ws_size, hipStream_t stream) {
  const float* left = (const float*)d_in[0];
  const float* right = (const float*)d_in[1];
  const float* w1 = (const float*)d_in[2];
  const float* b1 = (const float*)d_in[3];
  const float* g1 = (const float*)d_in[4];
  const float* be1 = (const float*)d_in[5];
  const float* m1 = (const float*)d_in[6];
  const float* v1 = (const float*)d_in[7];
  const float* w2 = (const float*)d_in[8];
  const float* b2 = (const float*)d_in[9];
  const float* g2 = (const float*)d_in[10];
  const float* be2 = (const float*)d_in[11];
  const float* m2 = (const float*)d_in[12];
  const float* v2 = (const float*)d_in[13];
  const float* w3 = (const float*)d_in[14];
  const float* b3 = (const float*)d_in[15];
  const float* g3 = (const float*)d_in[16];
  const float* be3 = (const float*)d_in[17];
  const float* m3 = (const float*)d_in[18];
  const float* v3 = (const float*)d_in[19];
  const float* w4 = (const float*)d_in[20];
  const float* b4 = (const float*)d_in[21];

  // Workspace:
  //  [0, 14680064)   cost_t bf16 [128][256][224]
  //  region: +0 pw1 (262144) | +262144 pb2 (65536) | +327680 pb3 (65536)
  //          +393216 o1_t bf16 [128][256][64] (4194304)
  char* ws = (char*)d_ws;
  unsigned short* cost_t = (unsigned short*)ws;
  char* region = ws + 14680064;
  unsigned short* pw1 = (unsigned short*)(region + 0);
  unsigned short* pb2 = (unsigned short*)(region + 262144);
  unsigned short* pb3 = (unsigned short*)(region + 327680);
  unsigned short* o1t = (unsigned short*)(region + 393216);
  float* o4 = (float*)d_out;

  k1_pack_cv<<<1106, 256, 0, stream>>>(left, right, w1, w2, w3, pw1, pb2, pb3,
                                       cost_t);
  conv1_mfma_kernel<<<dim3(4, 64), 256, 0, stream>>>(cost_t, pw1, b1, g1, be1,
                                                     m1, v1, o1t);
  k3_fused<<<dim3(4, 64), 256, 0, stream>>>(o1t, pb2, pb3, b2, g2, be2, m2, v2,
                                            b3, g3, be3, m3, v3, w4, b4, o4);
}